// Round 2
// baseline (2054.434 us; speedup 1.0000x reference)
//
#include <hip/hip_runtime.h>
#include <hip/hip_bf16.h>
#include <math.h>

#define NN 50000
#define NE 500000
#define HID 128
#define EDGE_C 64
#define IN_C 128
#define TASKS 8
#define LAYERS 3

// ---------------- CSR build ----------------
__global__ void zero_i32_kernel(int* p, int n) {
    int i = blockIdx.x * 256 + threadIdx.x;
    if (i < n) p[i] = 0;
}

__global__ void hist_kernel(const int* __restrict__ dst, int* __restrict__ cnt, int E) {
    int e = blockIdx.x * 256 + threadIdx.x;
    if (e < E) atomicAdd(&cnt[dst[e]], 1);
}

__global__ __launch_bounds__(1024) void scan_kernel(const int* __restrict__ cnt,
                                                    int* __restrict__ row_ptr, int n) {
    __shared__ int buf[1024];
    int carry = 0;
    for (int base = 0; base < n; base += 1024) {
        int i = base + (int)threadIdx.x;
        int v = (i < n) ? cnt[i] : 0;
        buf[threadIdx.x] = v;
        __syncthreads();
        for (int off = 1; off < 1024; off <<= 1) {
            int t = (threadIdx.x >= (unsigned)off) ? buf[threadIdx.x - off] : 0;
            __syncthreads();
            buf[threadIdx.x] += t;
            __syncthreads();
        }
        int incl = buf[threadIdx.x];
        if (i < n) row_ptr[i] = carry + incl - v;  // exclusive
        carry += buf[1023];
        __syncthreads();
    }
    if (threadIdx.x == 0) row_ptr[n] = carry;
}

__global__ void pos_kernel(const int* __restrict__ dst, const int* __restrict__ row_ptr,
                           int* __restrict__ cnt, int* __restrict__ pos, int E) {
    int e = blockIdx.x * 256 + threadIdx.x;
    if (e < E) {
        int d = dst[e];
        int off = atomicAdd(&cnt[d], 1);
        pos[e] = row_ptr[d] + off;
    }
}

// ---------------- tiled f32 GEMM: C[M,N] = A[M,K] @ B[K,N] + bias ----------------
// EPI 0: plain store to C (row stride N)
// EPI 1: msg epilogue: row e -> s=src[e]; v=relu(h[s]+acc+bias)+1e-7; store C[pos[e]*128 + n]
// ATRANS: A-element transform a = relu(a*aScale[k]+aShift[k])  (relu(BN) fused into A-load)
template <int EPI, bool ATRANS>
__global__ __launch_bounds__(256) void gemm_f32(
    const float* __restrict__ A, const float* __restrict__ B,
    const float* __restrict__ bias, float* __restrict__ C,
    int M, int N, int K,
    const int* __restrict__ src, const int* __restrict__ pos,
    const float* __restrict__ hbase, int hstride,
    const float* __restrict__ aScale, const float* __restrict__ aShift) {
    constexpr int BM = 64, BN = 64, BK = 16;
    __shared__ float As[BK][BM + 4];
    __shared__ float Bs[BK][BN];
    const int tid = threadIdx.x;
    const int tx = tid & 15;   // N dir (4 cols each)
    const int ty = tid >> 4;   // M dir (4 rows each)
    const int m0 = blockIdx.x * BM;
    const int n0 = blockIdx.y * BN;
    const int lm = tid >> 2;            // A-load row 0..63
    const int lk4 = (tid & 3) * 4;      // A-load k offset
    const int lkb = tid >> 4;           // B-load k 0..15
    const int ln4 = (tid & 15) * 4;     // B-load n offset

    float acc[4][4] = {};

    for (int k0 = 0; k0 < K; k0 += BK) {
        // --- load A tile (transposed into LDS) ---
        float4 av = make_float4(0.f, 0.f, 0.f, 0.f);
        int gm = m0 + lm;
        if (gm < M) av = *(const float4*)(A + (size_t)gm * K + (k0 + lk4));
        if (ATRANS) {
            int kk = k0 + lk4;
            av.x = fmaxf(fmaf(av.x, aScale[kk + 0], aShift[kk + 0]), 0.f);
            av.y = fmaxf(fmaf(av.y, aScale[kk + 1], aShift[kk + 1]), 0.f);
            av.z = fmaxf(fmaf(av.z, aScale[kk + 2], aShift[kk + 2]), 0.f);
            av.w = fmaxf(fmaf(av.w, aScale[kk + 3], aShift[kk + 3]), 0.f);
        }
        As[lk4 + 0][lm] = av.x;
        As[lk4 + 1][lm] = av.y;
        As[lk4 + 2][lm] = av.z;
        As[lk4 + 3][lm] = av.w;
        // --- load B tile ---
        float4 bv = *(const float4*)(B + (size_t)(k0 + lkb) * N + n0 + ln4);
        *(float4*)&Bs[lkb][ln4] = bv;
        __syncthreads();
#pragma unroll
        for (int k = 0; k < BK; k++) {
            float4 a = *(const float4*)&As[k][ty * 4];
            float4 b = *(const float4*)&Bs[k][tx * 4];
            float ar[4] = {a.x, a.y, a.z, a.w};
            float br[4] = {b.x, b.y, b.z, b.w};
#pragma unroll
            for (int i = 0; i < 4; i++)
#pragma unroll
                for (int j = 0; j < 4; j++) acc[i][j] = fmaf(ar[i], br[j], acc[i][j]);
        }
        __syncthreads();
    }

    const int gn = n0 + tx * 4;
    float4 bb = *(const float4*)(bias + gn);
    float bbr[4] = {bb.x, bb.y, bb.z, bb.w};
#pragma unroll
    for (int i = 0; i < 4; i++) {
        int gm = m0 + ty * 4 + i;
        if (gm >= M) continue;
        float4 o;
        o.x = acc[i][0] + bbr[0];
        o.y = acc[i][1] + bbr[1];
        o.z = acc[i][2] + bbr[2];
        o.w = acc[i][3] + bbr[3];
        if (EPI == 1) {
            int s = src[gm];
            const float* hp = hbase + (size_t)s * hstride + gn;
            float4 hv = *(const float4*)hp;
            o.x = fmaxf(o.x + hv.x, 0.f) + 1e-7f;
            o.y = fmaxf(o.y + hv.y, 0.f) + 1e-7f;
            o.z = fmaxf(o.z + hv.z, 0.f) + 1e-7f;
            o.w = fmaxf(o.w + hv.w, 0.f) + 1e-7f;
            *(float4*)(C + (size_t)pos[gm] * HID + gn) = o;
        } else {
            *(float4*)(C + (size_t)gm * N + gn) = o;
        }
    }
}

// ---------------- softmax aggregation (online, one wave per node) + y = h + agg ----------------
__global__ __launch_bounds__(256) void agg_y_kernel(const float* __restrict__ msg,
                                                    const int* __restrict__ row_ptr,
                                                    const float* __restrict__ hbase, int hstride,
                                                    float* __restrict__ y, int nnodes) {
    int warp = threadIdx.x >> 6;
    int lane = threadIdx.x & 63;
    int node = blockIdx.x * 4 + warp;
    if (node >= nnodes) return;
    int beg = row_ptr[node], end = row_ptr[node + 1];
    float m0 = -INFINITY, m1 = -INFINITY;
    float d0 = 0.f, d1 = 0.f, s0 = 0.f, s1 = 0.f;
    const float* p = msg + (size_t)beg * HID + lane * 2;
    for (int e = beg; e < end; ++e, p += HID) {
        float2 v = *(const float2*)p;
        float nm0 = fmaxf(m0, v.x);
        float sc0 = __expf(m0 - nm0);
        float e0 = __expf(v.x - nm0);
        d0 = d0 * sc0 + e0;
        s0 = fmaf(v.x, e0, s0 * sc0);
        m0 = nm0;
        float nm1 = fmaxf(m1, v.y);
        float sc1 = __expf(m1 - nm1);
        float e1 = __expf(v.y - nm1);
        d1 = d1 * sc1 + e1;
        s1 = fmaf(v.y, e1, s1 * sc1);
        m1 = nm1;
    }
    float a0 = s0 / (d0 + 1e-16f);
    float a1 = s1 / (d1 + 1e-16f);
    int c = lane * 2;
    const float* hp = hbase + (size_t)node * hstride + c;
    float2 hv = *(const float2*)hp;
    float2 o;
    o.x = hv.x + a0;
    o.y = hv.y + a1;
    *(float2*)(y + (size_t)node * HID + c) = o;
}

// ---------------- BatchNorm stats (two-stage, no atomics) ----------------
__global__ __launch_bounds__(256) void bn_stage1(const float* __restrict__ X, int M, int C,
                                                 float* __restrict__ part) {
    int col = threadIdx.x % C;
    int sub = threadIdx.x / C;
    int R = 256 / C;
    int rows_per_block = (M + gridDim.x - 1) / gridDim.x;
    int r0 = blockIdx.x * rows_per_block;
    int r1 = min(M, r0 + rows_per_block);
    float s = 0.f, q = 0.f;
    for (int r = r0 + sub; r < r1; r += R) {
        float v = X[(size_t)r * C + col];
        s += v;
        q = fmaf(v, v, q);
    }
    __shared__ float ls[256], lq[256];
    ls[threadIdx.x] = s;
    lq[threadIdx.x] = q;
    __syncthreads();
    if (sub == 0) {
        for (int k = 1; k < R; k++) {
            s += ls[col + k * C];
            q += lq[col + k * C];
        }
        part[(size_t)blockIdx.x * C + col] = s;
        part[(size_t)(gridDim.x + blockIdx.x) * C + col] = q;
    }
}

// stage2: one block; reduce partials, emit scale/shift so bn(x) = x*scale + shift
__global__ void bn_stage2(const float* __restrict__ part, int NB, int C, int M,
                          const float* __restrict__ g, const float* __restrict__ b,
                          float* __restrict__ scale, float* __restrict__ shift) {
    int col = threadIdx.x;
    if (col >= C) return;
    float s = 0.f, q = 0.f;
    for (int k = 0; k < NB; k++) {
        s += part[(size_t)k * C + col];
        q += part[(size_t)(NB + k) * C + col];
    }
    float inv = 1.f / (float)M;
    float mu = s * inv;
    float var = fmaf(q, inv, -mu * mu);
    float sc = g[col] * rsqrtf(var + 1e-5f);
    scale[col] = sc;
    shift[col] = b[col] - mu * sc;
}

// ---------------- h update: h_l = relu(bn(graw)) (+ h_{l-1}) into inter columns ----------------
__global__ void update_kernel(const float* __restrict__ graw, const float* __restrict__ scale,
                              const float* __restrict__ shift, const float* __restrict__ prev,
                              float* __restrict__ out, int total) {
    int i = blockIdx.x * 256 + threadIdx.x;
    if (i >= total) return;
    int node = i >> 7;
    int c = i & 127;
    float v = fmaxf(fmaf(graw[i], scale[c], shift[c]), 0.f);
    if (prev) v += prev[(size_t)node * (LAYERS * HID) + c];
    out[(size_t)node * (LAYERS * HID) + c] = v;
}

// ---------------- prediction head: out[n,t] = concat_row(n) @ pred_W + pred_b ----------------
__global__ __launch_bounds__(256) void pred_kernel(const float* __restrict__ inter,
                                                   const float* __restrict__ W,
                                                   const float* __restrict__ b,
                                                   float* __restrict__ out, int nnodes) {
    __shared__ float ws[LAYERS * HID * TASKS];  // 384*8 = 12 KB
    for (int i = threadIdx.x; i < LAYERS * HID * TASKS; i += 256) ws[i] = W[i];
    __syncthreads();
    int t = threadIdx.x & 7;
    int nl = threadIdx.x >> 3;
    int node = blockIdx.x * 32 + nl;
    if (node >= nnodes) return;
    const float* row = inter + (size_t)node * (LAYERS * HID);
    float acc = b[t];
    for (int k = 0; k < LAYERS * HID; k += 4) {
        float4 a = *(const float4*)(row + k);
        acc = fmaf(a.x, ws[(k + 0) * TASKS + t], acc);
        acc = fmaf(a.y, ws[(k + 1) * TASKS + t], acc);
        acc = fmaf(a.z, ws[(k + 2) * TASKS + t], acc);
        acc = fmaf(a.w, ws[(k + 3) * TASKS + t], acc);
    }
    out[(size_t)node * TASKS + t] = acc;
}

// ---------------- launch ----------------
extern "C" void kernel_launch(void* const* d_in, const int* in_sizes, int n_in,
                              void* d_out, int out_size, void* d_ws, size_t ws_size,
                              hipStream_t stream) {
    const float* x = (const float*)d_in[0];
    const int* ei = (const int*)d_in[1];
    const float* edge_attr = (const float*)d_in[2];
    const float* enc_W = (const float*)d_in[3];
    const float* enc_b = (const float*)d_in[4];
    const float* leW = (const float*)d_in[5];
    const float* leb = (const float*)d_in[6];
    const float* W1 = (const float*)d_in[7];
    const float* b1 = (const float*)d_in[8];
    const float* ng = (const float*)d_in[9];
    const float* nb = (const float*)d_in[10];
    const float* W2 = (const float*)d_in[11];
    const float* b2 = (const float*)d_in[12];
    const float* og = (const float*)d_in[13];
    const float* ob = (const float*)d_in[14];
    const float* pW = (const float*)d_in[15];
    const float* pb = (const float*)d_in[16];
    float* out = (float*)d_out;

    const int E = in_sizes[1] / 2;
    const int* src = ei;
    const int* dst = ei + E;

    // workspace carve-up (256B aligned) with overflow guard
    char* w = (char*)d_ws;
    size_t off = 0;
    auto alloc = [&](size_t bytes) {
        void* p = w + off;
        off = (off + bytes + 255) & ~(size_t)255;
        return p;
    };
    float* inter = (float*)alloc((size_t)NN * LAYERS * HID * 4);  // 76.8 MB
    float* h0 = (float*)alloc((size_t)NN * HID * 4);              // 25.6 MB
    float* msg = (float*)alloc((size_t)NE * HID * 4);             // 256 MB
    float* y = (float*)alloc((size_t)NN * HID * 4);               // 25.6 MB
    float* z = (float*)alloc((size_t)NN * 2 * HID * 4);           // 51.2 MB
    float* graw = (float*)alloc((size_t)NN * HID * 4);            // 25.6 MB
    int* row_ptr = (int*)alloc((size_t)(NN + 1) * 4);
    int* cnt = (int*)alloc((size_t)NN * 4);
    int* pos = (int*)alloc((size_t)NE * 4);
    float* part = (float*)alloc((size_t)2 * 256 * 256 * 4);
    float* bnsc = (float*)alloc(256 * 4);
    float* bnsh = (float*)alloc(256 * 4);
    float* bnsc2 = (float*)alloc(128 * 4);
    float* bnsh2 = (float*)alloc(128 * 4);
    if (off > ws_size) return;  // insufficient workspace: fail validation, don't corrupt

    // ---- CSR build ----
    zero_i32_kernel<<<(NN + 255) / 256, 256, 0, stream>>>(cnt, NN);
    hist_kernel<<<(E + 255) / 256, 256, 0, stream>>>(dst, cnt, E);
    scan_kernel<<<1, 1024, 0, stream>>>(cnt, row_ptr, NN);
    zero_i32_kernel<<<(NN + 255) / 256, 256, 0, stream>>>(cnt, NN);
    pos_kernel<<<(E + 255) / 256, 256, 0, stream>>>(dst, row_ptr, cnt, pos, E);

    // ---- encoder: h0 = x @ enc_W + enc_b ----
    {
        dim3 grid((NN + 63) / 64, HID / 64);
        gemm_f32<0, false><<<grid, 256, 0, stream>>>(x, enc_W, enc_b, h0, NN, HID, IN_C,
                                                     nullptr, nullptr, nullptr, 0, nullptr, nullptr);
    }

    const float* hcur = h0;
    int hstride = HID;

    for (int l = 0; l < LAYERS; l++) {
        // edge GEMM + msg epilogue (gather h[src], relu, +eps, scatter to CSR slot)
        {
            dim3 grid((E + 63) / 64, HID / 64);
            gemm_f32<1, false><<<grid, 256, 0, stream>>>(
                edge_attr, leW + (size_t)l * EDGE_C * HID, leb + (size_t)l * HID, msg,
                E, HID, EDGE_C, src, pos, hcur, hstride, nullptr, nullptr);
        }
        // softmax aggregation + y = h + agg
        agg_y_kernel<<<(NN + 3) / 4, 256, 0, stream>>>(msg, row_ptr, hcur, hstride, y, NN);
        // z = y @ W1 + b1   (50000 x 256)
        {
            dim3 grid((NN + 63) / 64, (2 * HID) / 64);
            gemm_f32<0, false><<<grid, 256, 0, stream>>>(
                y, W1 + (size_t)l * HID * 2 * HID, b1 + (size_t)l * 2 * HID, z,
                NN, 2 * HID, HID, nullptr, nullptr, nullptr, 0, nullptr, nullptr);
        }
        // BN over z (C=256) -> scale/shift
        bn_stage1<<<256, 256, 0, stream>>>(z, NN, 2 * HID, part);
        bn_stage2<<<1, 256, 0, stream>>>(part, 256, 2 * HID, NN,
                                         ng + (size_t)l * 2 * HID, nb + (size_t)l * 2 * HID,
                                         bnsc, bnsh);
        // graw = relu(bn(z)) @ W2 + b2   (A-transform fused)
        {
            dim3 grid((NN + 63) / 64, HID / 64);
            gemm_f32<0, true><<<grid, 256, 0, stream>>>(
                z, W2 + (size_t)l * 2 * HID * HID, b2 + (size_t)l * HID, graw,
                NN, HID, 2 * HID, nullptr, nullptr, nullptr, 0, bnsc, bnsh);
        }
        // BN over graw (C=128) -> scale/shift
        bn_stage1<<<256, 256, 0, stream>>>(graw, NN, HID, part);
        bn_stage2<<<1, 128, 0, stream>>>(part, 256, HID, NN,
                                         og + (size_t)l * HID, ob + (size_t)l * HID,
                                         bnsc2, bnsh2);
        // h_l = relu(bn(graw)) (+ h_{l-1}), write into inter column block l
        {
            const float* prev = (l == 0) ? nullptr : (inter + (size_t)(l - 1) * HID);
            update_kernel<<<(NN * HID + 255) / 256, 256, 0, stream>>>(
                graw, bnsc2, bnsh2, prev, inter + (size_t)l * HID, NN * HID);
        }
        hcur = inter + (size_t)l * HID;
        hstride = LAYERS * HID;
    }

    // prediction head
    pred_kernel<<<(NN + 31) / 32, 256, 0, stream>>>(inter, pW, pb, out, NN);
    (void)out_size;
    (void)n_in;
}

// Round 3
// 1857.008 us; speedup vs baseline: 1.1063x; 1.1063x over previous
//
#include <hip/hip_runtime.h>
#include <math.h>

#define NN 50000
#define NE 500000
#define HID 128
#define EDGE_C 64
#define IN_C 128
#define TASKS 8
#define LAYERS 3

typedef unsigned short u16;
typedef unsigned int u32;
typedef __attribute__((ext_vector_type(8))) short s16x8;
typedef __attribute__((ext_vector_type(4))) float f32x4;

__device__ __forceinline__ u16 f2bf(float f) {
    u32 u = __float_as_uint(f);
    u += 0x7fffu + ((u >> 16) & 1u);  // RNE
    return (u16)(u >> 16);
}
__device__ __forceinline__ float bf2f(u16 h) {
    return __uint_as_float(((u32)h) << 16);
}
__device__ __forceinline__ u32 pack2(u16 lo, u16 hi) { return (u32)lo | ((u32)hi << 16); }

// ---------------- CSR build ----------------
__global__ void zero_i32_kernel(int* p, int n) {
    int i = blockIdx.x * 256 + threadIdx.x;
    if (i < n) p[i] = 0;
}

__global__ void hist_kernel(const int* __restrict__ dst, int* __restrict__ cnt, int E) {
    int e = blockIdx.x * 256 + threadIdx.x;
    if (e < E) atomicAdd(&cnt[dst[e]], 1);
}

__global__ __launch_bounds__(1024) void scan_kernel(const int* __restrict__ cnt,
                                                    int* __restrict__ row_ptr, int n) {
    __shared__ int buf[1024];
    int carry = 0;
    for (int base = 0; base < n; base += 1024) {
        int i = base + (int)threadIdx.x;
        int v = (i < n) ? cnt[i] : 0;
        buf[threadIdx.x] = v;
        __syncthreads();
        for (int off = 1; off < 1024; off <<= 1) {
            int t = (threadIdx.x >= (unsigned)off) ? buf[threadIdx.x - off] : 0;
            __syncthreads();
            buf[threadIdx.x] += t;
            __syncthreads();
        }
        int incl = buf[threadIdx.x];
        if (i < n) row_ptr[i] = carry + incl - v;  // exclusive
        carry += buf[1023];
        __syncthreads();
    }
    if (threadIdx.x == 0) row_ptr[n] = carry;
}

__global__ void pos_kernel(const int* __restrict__ dst, const int* __restrict__ row_ptr,
                           int* __restrict__ cnt, int* __restrict__ pos, int E) {
    int e = blockIdx.x * 256 + threadIdx.x;
    if (e < E) {
        int d = dst[e];
        int off = atomicAdd(&cnt[d], 1);
        pos[e] = row_ptr[d] + off;
    }
}

// ---------------- prep: f32 -> bf16 elementwise (8 per thread) ----------------
__global__ void conv_bf16_kernel(const float* __restrict__ X, u16* __restrict__ Y, int total8) {
    int i = blockIdx.x * 256 + threadIdx.x;
    if (i >= total8) return;
    const float* p = X + (size_t)i * 8;
    float4 a = *(const float4*)p;
    float4 b = *(const float4*)(p + 4);
    uint4 o;
    o.x = pack2(f2bf(a.x), f2bf(a.y));
    o.y = pack2(f2bf(a.z), f2bf(a.w));
    o.z = pack2(f2bf(b.x), f2bf(b.y));
    o.w = pack2(f2bf(b.z), f2bf(b.w));
    *(uint4*)(Y + (size_t)i * 8) = o;
}

// ---------------- prep: weight transpose+convert W[K][N] f32 -> Bt[N][K] bf16 ----------------
__global__ void wconv_kernel(const float* __restrict__ W, u16* __restrict__ Bt, int K, int N) {
    int i = blockIdx.x * 256 + threadIdx.x;
    if (i >= K * N) return;
    int n = i / K, k = i % K;
    Bt[i] = f2bf(W[(size_t)k * N + n]);
}

// ---------------- bf16 MFMA GEMM: C[M,N] = A[M,K] @ Bt[N,K]^T + bias ----------------
// ASRC: 0 = A bf16; 1 = A f32 (convert); 2 = A f32 with relu(a*scale[k]+shift[k]) (fused BN)
// EPI:  0 = store f32 Cf[M,N]
//       1 = msg: v=relu(acc+bias+hb[src[gm]][col])+1e-7 -> bf16 Cb[pos[gm]*HID+col]
//       3 = store bf16 Cb[M,N]
template <int ASRC, int EPI>
__global__ __launch_bounds__(256) void mfma_gemm(
    const void* __restrict__ Av, const u16* __restrict__ Bt,
    const float* __restrict__ bias, float* __restrict__ Cf, u16* __restrict__ Cb,
    int M, int N, int K,
    const int* __restrict__ src, const int* __restrict__ pos,
    const u16* __restrict__ hb,
    const float* __restrict__ aScale, const float* __restrict__ aShift) {
    __shared__ u16 As[128][40];  // +8 pad: row stride 80B -> ~2-4 way max on ds_read_b128
    __shared__ u16 Bs[64][40];
    const int tid = threadIdx.x;
    const int lane = tid & 63;
    const int wid = tid >> 6;
    const int wm = wid >> 1, wn = wid & 1;
    const int m0 = blockIdx.x * 128;
    const int n0 = blockIdx.y * 64;
    const int lr = lane & 15;            // frag row (A) / col (B/D)
    const int lk = (lane >> 4) * 8;      // frag k offset

    f32x4 acc[4][2] = {};

    for (int k0 = 0; k0 < K; k0 += 32) {
        // ---- stage A (2 chunks of 8 bf16 per thread) ----
#pragma unroll
        for (int it = 0; it < 2; ++it) {
            int c = tid + 256 * it;
            int row = c >> 2, ko = (c & 3) * 8;
            int gm = m0 + row;
            uint4 t = make_uint4(0u, 0u, 0u, 0u);
            if (ASRC == 0) {
                if (gm < M) t = *(const uint4*)((const u16*)Av + (size_t)gm * K + k0 + ko);
            } else {
                float v[8] = {};
                if (gm < M) {
                    const float* ap = (const float*)Av + (size_t)gm * K + k0 + ko;
                    *(float4*)&v[0] = *(const float4*)ap;
                    *(float4*)&v[4] = *(const float4*)(ap + 4);
                }
                if (ASRC == 2) {
#pragma unroll
                    for (int j = 0; j < 8; ++j) {
                        int kk = k0 + ko + j;
                        v[j] = fmaxf(fmaf(v[j], aScale[kk], aShift[kk]), 0.f);
                    }
                }
                t.x = pack2(f2bf(v[0]), f2bf(v[1]));
                t.y = pack2(f2bf(v[2]), f2bf(v[3]));
                t.z = pack2(f2bf(v[4]), f2bf(v[5]));
                t.w = pack2(f2bf(v[6]), f2bf(v[7]));
            }
            *(uint4*)&As[row][ko] = t;
        }
        // ---- stage B (1 chunk per thread) ----
        {
            int row = tid >> 2, ko = (tid & 3) * 8;
            *(uint4*)&Bs[row][ko] =
                *(const uint4*)(Bt + (size_t)(n0 + row) * K + k0 + ko);
        }
        __syncthreads();
        s16x8 a[4], b[2];
#pragma unroll
        for (int mf = 0; mf < 4; ++mf) a[mf] = *(const s16x8*)&As[wm * 64 + mf * 16 + lr][lk];
#pragma unroll
        for (int nf = 0; nf < 2; ++nf) b[nf] = *(const s16x8*)&Bs[wn * 32 + nf * 16 + lr][lk];
#pragma unroll
        for (int mf = 0; mf < 4; ++mf)
#pragma unroll
            for (int nf = 0; nf < 2; ++nf)
                acc[mf][nf] = __builtin_amdgcn_mfma_f32_16x16x32_bf16(a[mf], b[nf], acc[mf][nf], 0, 0, 0);
        __syncthreads();
    }

    // ---- epilogue ----
#pragma unroll
    for (int nf = 0; nf < 2; ++nf) {
        int col = n0 + wn * 32 + nf * 16 + lr;
        float bcol = bias[col];
#pragma unroll
        for (int mf = 0; mf < 4; ++mf) {
#pragma unroll
            for (int r = 0; r < 4; ++r) {
                int gm = m0 + wm * 64 + mf * 16 + (lane >> 4) * 4 + r;
                if (gm >= M) continue;
                float v = acc[mf][nf][r] + bcol;
                if (EPI == 0) {
                    Cf[(size_t)gm * N + col] = v;
                } else if (EPI == 1) {
                    int s = src[gm];
                    v = fmaxf(v + bf2f(hb[(size_t)s * HID + col]), 0.f) + 1e-7f;
                    Cb[(size_t)pos[gm] * HID + col] = f2bf(v);
                } else {
                    Cb[(size_t)gm * N + col] = f2bf(v);
                }
            }
        }
    }
}

// ---------------- softmax aggregation (online, wave/node) + y = h + agg (bf16) ----------------
__global__ __launch_bounds__(256) void agg_y_kernel(const u16* __restrict__ msg,
                                                    const int* __restrict__ row_ptr,
                                                    const u16* __restrict__ hb,
                                                    u16* __restrict__ y, int nnodes) {
    int w = threadIdx.x >> 6;
    int lane = threadIdx.x & 63;
    int node = blockIdx.x * 4 + w;
    if (node >= nnodes) return;
    int beg = row_ptr[node], end = row_ptr[node + 1];
    float m0 = -INFINITY, m1 = -INFINITY;
    float d0 = 0.f, d1 = 0.f, s0 = 0.f, s1 = 0.f;
    const u16* p = msg + (size_t)beg * HID + lane * 2;
    for (int e = beg; e < end; ++e, p += HID) {
        u32 u = *(const u32*)p;
        float vx = bf2f((u16)u), vy = bf2f((u16)(u >> 16));
        float nm0 = fmaxf(m0, vx);
        float sc0 = __expf(m0 - nm0);
        float e0 = __expf(vx - nm0);
        d0 = d0 * sc0 + e0;
        s0 = fmaf(vx, e0, s0 * sc0);
        m0 = nm0;
        float nm1 = fmaxf(m1, vy);
        float sc1 = __expf(m1 - nm1);
        float e1 = __expf(vy - nm1);
        d1 = d1 * sc1 + e1;
        s1 = fmaf(vy, e1, s1 * sc1);
        m1 = nm1;
    }
    float a0 = s0 / (d0 + 1e-16f);
    float a1 = s1 / (d1 + 1e-16f);
    u32 hu = *(const u32*)(hb + (size_t)node * HID + lane * 2);
    float o0 = bf2f((u16)hu) + a0;
    float o1 = bf2f((u16)(hu >> 16)) + a1;
    *(u32*)(y + (size_t)node * HID + lane * 2) = pack2(f2bf(o0), f2bf(o1));
}

// ---------------- BatchNorm stats (two-stage, no atomics) ----------------
__global__ __launch_bounds__(256) void bn_stage1(const float* __restrict__ X, int M, int C,
                                                 float* __restrict__ part) {
    int col = threadIdx.x % C;
    int sub = threadIdx.x / C;
    int R = 256 / C;
    int rows_per_block = (M + gridDim.x - 1) / gridDim.x;
    int r0 = blockIdx.x * rows_per_block;
    int r1 = min(M, r0 + rows_per_block);
    float s = 0.f, q = 0.f;
    for (int r = r0 + sub; r < r1; r += R) {
        float v = X[(size_t)r * C + col];
        s += v;
        q = fmaf(v, v, q);
    }
    __shared__ float ls[256], lq[256];
    ls[threadIdx.x] = s;
    lq[threadIdx.x] = q;
    __syncthreads();
    if (sub == 0) {
        for (int k = 1; k < R; k++) {
            s += ls[col + k * C];
            q += lq[col + k * C];
        }
        part[(size_t)blockIdx.x * C + col] = s;
        part[(size_t)(gridDim.x + blockIdx.x) * C + col] = q;
    }
}

__global__ void bn_stage2(const float* __restrict__ part, int NB, int C, int M,
                          const float* __restrict__ g, const float* __restrict__ b,
                          float* __restrict__ scale, float* __restrict__ shift) {
    int col = threadIdx.x;
    if (col >= C) return;
    float s = 0.f, q = 0.f;
    for (int k = 0; k < NB; k++) {
        s += part[(size_t)k * C + col];
        q += part[(size_t)(NB + k) * C + col];
    }
    float inv = 1.f / (float)M;
    float mu = s * inv;
    float var = fmaf(q, inv, -mu * mu);
    float sc = g[col] * rsqrtf(var + 1e-5f);
    scale[col] = sc;
    shift[col] = b[col] - mu * sc;
}

// ---------------- h update: inter block + bf16 copy for next layer's gather ----------------
__global__ void update_kernel(const float* __restrict__ graw, const float* __restrict__ scale,
                              const float* __restrict__ shift, const float* __restrict__ prev,
                              float* __restrict__ out, u16* __restrict__ hb, int total) {
    int i = blockIdx.x * 256 + threadIdx.x;
    if (i >= total) return;
    int node = i >> 7;
    int c = i & 127;
    float v = fmaxf(fmaf(graw[i], scale[c], shift[c]), 0.f);
    if (prev) v += prev[(size_t)node * (LAYERS * HID) + c];
    out[(size_t)node * (LAYERS * HID) + c] = v;
    hb[i] = f2bf(v);
}

// ---------------- prediction head ----------------
__global__ __launch_bounds__(256) void pred_kernel(const float* __restrict__ inter,
                                                   const float* __restrict__ W,
                                                   const float* __restrict__ b,
                                                   float* __restrict__ out, int nnodes) {
    __shared__ float ws[LAYERS * HID * TASKS];
    for (int i = threadIdx.x; i < LAYERS * HID * TASKS; i += 256) ws[i] = W[i];
    __syncthreads();
    int t = threadIdx.x & 7;
    int nl = threadIdx.x >> 3;
    int node = blockIdx.x * 32 + nl;
    if (node >= nnodes) return;
    const float* row = inter + (size_t)node * (LAYERS * HID);
    float acc = b[t];
    for (int k = 0; k < LAYERS * HID; k += 4) {
        float4 a = *(const float4*)(row + k);
        acc = fmaf(a.x, ws[(k + 0) * TASKS + t], acc);
        acc = fmaf(a.y, ws[(k + 1) * TASKS + t], acc);
        acc = fmaf(a.z, ws[(k + 2) * TASKS + t], acc);
        acc = fmaf(a.w, ws[(k + 3) * TASKS + t], acc);
    }
    out[(size_t)node * TASKS + t] = acc;
}

// ---------------- launch ----------------
extern "C" void kernel_launch(void* const* d_in, const int* in_sizes, int n_in,
                              void* d_out, int out_size, void* d_ws, size_t ws_size,
                              hipStream_t stream) {
    const float* x = (const float*)d_in[0];
    const int* ei = (const int*)d_in[1];
    const float* edge_attr = (const float*)d_in[2];
    const float* enc_W = (const float*)d_in[3];
    const float* enc_b = (const float*)d_in[4];
    const float* leW = (const float*)d_in[5];
    const float* leb = (const float*)d_in[6];
    const float* W1 = (const float*)d_in[7];
    const float* b1 = (const float*)d_in[8];
    const float* ng = (const float*)d_in[9];
    const float* nb = (const float*)d_in[10];
    const float* W2 = (const float*)d_in[11];
    const float* b2 = (const float*)d_in[12];
    const float* og = (const float*)d_in[13];
    const float* ob = (const float*)d_in[14];
    const float* pW = (const float*)d_in[15];
    const float* pb = (const float*)d_in[16];
    float* out = (float*)d_out;

    const int E = in_sizes[1] / 2;
    const int* src = ei;
    const int* dst = ei + E;

    char* w = (char*)d_ws;
    size_t off = 0;
    auto alloc = [&](size_t bytes) {
        void* p = w + off;
        off = (off + bytes + 255) & ~(size_t)255;
        return p;
    };
    float* inter = (float*)alloc((size_t)NN * LAYERS * HID * 4);  // 76.8 MB
    u16* msg = (u16*)alloc((size_t)NE * HID * 2);                 // 128 MB
    u16* eab = (u16*)alloc((size_t)NE * EDGE_C * 2);              // 64 MB
    u16* hb = (u16*)alloc((size_t)NN * HID * 2);                  // 12.8 MB
    u16* yb = (u16*)alloc((size_t)NN * HID * 2);                  // 12.8 MB
    float* z = (float*)alloc((size_t)NN * 2 * HID * 4);           // 51.2 MB
    float* graw = (float*)alloc((size_t)NN * HID * 4);            // 25.6 MB
    u16* encWt = (u16*)alloc((size_t)IN_C * HID * 2);
    u16* leWt = (u16*)alloc((size_t)LAYERS * HID * EDGE_C * 2);
    u16* W1t = (u16*)alloc((size_t)LAYERS * 2 * HID * HID * 2);
    u16* W2t = (u16*)alloc((size_t)LAYERS * HID * 2 * HID * 2);
    int* row_ptr = (int*)alloc((size_t)(NN + 1) * 4);
    int* cnt = (int*)alloc((size_t)NN * 4);
    int* pos = (int*)alloc((size_t)NE * 4);
    float* part = (float*)alloc((size_t)2 * 256 * 256 * 4);
    float* bnsc = (float*)alloc(256 * 4);
    float* bnsh = (float*)alloc(256 * 4);
    float* bnsc2 = (float*)alloc(128 * 4);
    float* bnsh2 = (float*)alloc(128 * 4);
    if (off > ws_size) return;  // insufficient workspace: fail loudly, don't corrupt

    // ---- CSR build ----
    zero_i32_kernel<<<(NN + 255) / 256, 256, 0, stream>>>(cnt, NN);
    hist_kernel<<<(E + 255) / 256, 256, 0, stream>>>(dst, cnt, E);
    scan_kernel<<<1, 1024, 0, stream>>>(cnt, row_ptr, NN);
    zero_i32_kernel<<<(NN + 255) / 256, 256, 0, stream>>>(cnt, NN);
    pos_kernel<<<(E + 255) / 256, 256, 0, stream>>>(dst, row_ptr, cnt, pos, E);

    // ---- prep conversions ----
    conv_bf16_kernel<<<(E * EDGE_C / 8 + 255) / 256, 256, 0, stream>>>(edge_attr, eab,
                                                                        E * EDGE_C / 8);
    wconv_kernel<<<(IN_C * HID + 255) / 256, 256, 0, stream>>>(enc_W, encWt, IN_C, HID);
    for (int l = 0; l < LAYERS; l++) {
        wconv_kernel<<<(EDGE_C * HID + 255) / 256, 256, 0, stream>>>(
            leW + (size_t)l * EDGE_C * HID, leWt + (size_t)l * HID * EDGE_C, EDGE_C, HID);
        wconv_kernel<<<(HID * 2 * HID + 255) / 256, 256, 0, stream>>>(
            W1 + (size_t)l * HID * 2 * HID, W1t + (size_t)l * 2 * HID * HID, HID, 2 * HID);
        wconv_kernel<<<(2 * HID * HID + 255) / 256, 256, 0, stream>>>(
            W2 + (size_t)l * 2 * HID * HID, W2t + (size_t)l * HID * 2 * HID, 2 * HID, HID);
    }

    // ---- encoder: hb = bf16(x @ enc_W + enc_b) ----
    {
        dim3 grid((NN + 127) / 128, HID / 64);
        mfma_gemm<1, 3><<<grid, 256, 0, stream>>>(x, encWt, enc_b, nullptr, hb, NN, HID, IN_C,
                                                  nullptr, nullptr, nullptr, nullptr, nullptr);
    }

    for (int l = 0; l < LAYERS; l++) {
        // msg[pos[e]] = bf16(relu(ea@leW + leb + hb[src]) + 1e-7)
        {
            dim3 grid((E + 127) / 128, HID / 64);
            mfma_gemm<0, 1><<<grid, 256, 0, stream>>>(
                eab, leWt + (size_t)l * HID * EDGE_C, leb + (size_t)l * HID, nullptr, msg,
                E, HID, EDGE_C, src, pos, hb, nullptr, nullptr);
        }
        // softmax aggregation + y = h + agg (bf16)
        agg_y_kernel<<<(NN + 3) / 4, 256, 0, stream>>>(msg, row_ptr, hb, yb, NN);
        // z = y @ W1 + b1 (f32 out)
        {
            dim3 grid((NN + 127) / 128, (2 * HID) / 64);
            mfma_gemm<0, 0><<<grid, 256, 0, stream>>>(
                yb, W1t + (size_t)l * 2 * HID * HID, b1 + (size_t)l * 2 * HID, z, nullptr,
                NN, 2 * HID, HID, nullptr, nullptr, nullptr, nullptr, nullptr);
        }
        bn_stage1<<<256, 256, 0, stream>>>(z, NN, 2 * HID, part);
        bn_stage2<<<1, 256, 0, stream>>>(part, 256, 2 * HID, NN,
                                         ng + (size_t)l * 2 * HID, nb + (size_t)l * 2 * HID,
                                         bnsc, bnsh);
        // graw = relu(bn(z)) @ W2 + b2  (BN+relu fused into A staging)
        {
            dim3 grid((NN + 127) / 128, HID / 64);
            mfma_gemm<2, 0><<<grid, 256, 0, stream>>>(
                z, W2t + (size_t)l * HID * 2 * HID, b2 + (size_t)l * HID, graw, nullptr,
                NN, HID, 2 * HID, nullptr, nullptr, nullptr, bnsc, bnsh);
        }
        bn_stage1<<<256, 256, 0, stream>>>(graw, NN, HID, part);
        bn_stage2<<<1, 128, 0, stream>>>(part, 256, HID, NN,
                                         og + (size_t)l * HID, ob + (size_t)l * HID,
                                         bnsc2, bnsh2);
        {
            const float* prev = (l == 0) ? nullptr : (inter + (size_t)(l - 1) * HID);
            update_kernel<<<(NN * HID + 255) / 256, 256, 0, stream>>>(
                graw, bnsc2, bnsh2, prev, inter + (size_t)l * HID, hb, NN * HID);
        }
    }

    pred_kernel<<<(NN + 31) / 32, 256, 0, stream>>>(inter, pW, pb, out, NN);
    (void)out_size;
    (void)n_in;
}

// Round 4
// 1512.825 us; speedup vs baseline: 1.3580x; 1.2275x over previous
//
#include <hip/hip_runtime.h>
#include <math.h>

#define NN 50000
#define NE 500000
#define HID 128
#define EDGE_C 64
#define IN_C 128
#define TASKS 8
#define LAYERS 3

typedef unsigned short u16;
typedef unsigned int u32;
typedef __attribute__((ext_vector_type(8))) short s16x8;
typedef __attribute__((ext_vector_type(4))) float f32x4;

__device__ __forceinline__ u16 f2bf(float f) {
    u32 u = __float_as_uint(f);
    u += 0x7fffu + ((u >> 16) & 1u);  // RNE
    return (u16)(u >> 16);
}
__device__ __forceinline__ float bf2f(u16 h) {
    return __uint_as_float(((u32)h) << 16);
}
__device__ __forceinline__ u32 pack2(u16 lo, u16 hi) { return (u32)lo | ((u32)hi << 16); }

// ---------------- CSR build ----------------
__global__ void zero_i32_kernel(int* p, int n) {
    int i = blockIdx.x * 256 + threadIdx.x;
    if (i < n) p[i] = 0;
}

__global__ void hist_kernel(const int* __restrict__ dst, int* __restrict__ cnt, int E) {
    int e = blockIdx.x * 256 + threadIdx.x;
    if (e < E) atomicAdd(&cnt[dst[e]], 1);
}

// hierarchical exclusive scan: stage1 per-block scan -> excl into row_ptr + block sums
__global__ __launch_bounds__(256) void scan1_kernel(const int* __restrict__ cnt,
                                                    int* __restrict__ row_ptr,
                                                    int* __restrict__ bsum, int n) {
    __shared__ int buf[256];
    int i = blockIdx.x * 256 + threadIdx.x;
    int v = (i < n) ? cnt[i] : 0;
    buf[threadIdx.x] = v;
    __syncthreads();
    for (int off = 1; off < 256; off <<= 1) {
        int t = ((int)threadIdx.x >= off) ? buf[threadIdx.x - off] : 0;
        __syncthreads();
        buf[threadIdx.x] += t;
        __syncthreads();
    }
    if (i < n) row_ptr[i] = buf[threadIdx.x] - v;
    if (threadIdx.x == 255) bsum[blockIdx.x] = buf[255];
}

__global__ __launch_bounds__(256) void scan2_kernel(const int* __restrict__ bsum,
                                                    int* __restrict__ boff, int nb,
                                                    int* __restrict__ row_end) {
    __shared__ int buf[256];
    int v = ((int)threadIdx.x < nb) ? bsum[threadIdx.x] : 0;
    buf[threadIdx.x] = v;
    __syncthreads();
    for (int off = 1; off < 256; off <<= 1) {
        int t = ((int)threadIdx.x >= off) ? buf[threadIdx.x - off] : 0;
        __syncthreads();
        buf[threadIdx.x] += t;
        __syncthreads();
    }
    if ((int)threadIdx.x < nb) boff[threadIdx.x] = buf[threadIdx.x] - v;
    if ((int)threadIdx.x == nb - 1) *row_end = buf[threadIdx.x];
}

__global__ void scan3_kernel(int* __restrict__ row_ptr, const int* __restrict__ boff, int n) {
    int i = blockIdx.x * 256 + threadIdx.x;
    if (i < n) row_ptr[i] += boff[blockIdx.x];
}

__global__ void pos_kernel(const int* __restrict__ dst, const int* __restrict__ row_ptr,
                           int* __restrict__ cnt, int* __restrict__ pos, int E) {
    int e = blockIdx.x * 256 + threadIdx.x;
    if (e < E) {
        int d = dst[e];
        int off = atomicAdd(&cnt[d], 1);
        pos[e] = row_ptr[d] + off;
    }
}

__global__ void eperm_kernel(const int* __restrict__ pos, int* __restrict__ eperm, int E) {
    int e = blockIdx.x * 256 + threadIdx.x;
    if (e < E) eperm[pos[e]] = e;
}

// gather edge_attr into CSR order + convert to bf16; also src_csr. 16 threads/slot.
__global__ void gatherconv_kernel(const float* __restrict__ edge_attr,
                                  const int* __restrict__ eperm, const int* __restrict__ src,
                                  u16* __restrict__ eab, int* __restrict__ src_csr, int E) {
    int t = blockIdx.x * 256 + threadIdx.x;
    if (t >= E * 16) return;
    int slot = t >> 4, j = t & 15;
    int e = eperm[slot];
    float4 v = *(const float4*)(edge_attr + (size_t)e * EDGE_C + j * 4);
    u16 o[4] = {f2bf(v.x), f2bf(v.y), f2bf(v.z), f2bf(v.w)};
    *(uint2*)(eab + (size_t)slot * EDGE_C + j * 4) = *(uint2*)o;
    if (j == 0) src_csr[slot] = src[e];
}

// ---------------- prep: weight transpose+convert W[K][N] f32 -> Bt[N][K] bf16 ----------------
__global__ void wconv_kernel(const float* __restrict__ W, u16* __restrict__ Bt, int K, int N) {
    int i = blockIdx.x * 256 + threadIdx.x;
    if (i >= K * N) return;
    int n = i / K, k = i % K;
    Bt[i] = f2bf(W[(size_t)k * N + n]);
}

// ---------------- edge msg kernel: msg[slot] = bf16(relu(eab[slot]@leW + leb + hb[src_csr]) + 1e-7)
// 128x128 tile, K=64 staged once; LDS-staged epilogue for vectorized gather/stores.
__global__ __launch_bounds__(256) void edge_msg_kernel(
    const u16* __restrict__ eab, const u16* __restrict__ Wt, const float* __restrict__ bias,
    const int* __restrict__ src_csr, const u16* __restrict__ hb, u16* __restrict__ msg, int M) {
    __shared__ u16 lds[18432];  // 36 KB: As[128][72] + Bs[128][72]; reused as Cs[128][136]
    u16* As = lds;
    u16* Bs = lds + 128 * 72;
    const int tid = threadIdx.x;
    const int lane = tid & 63;
    const int wid = tid >> 6;
    const int wm = wid >> 1, wn = wid & 1;  // 2x2 waves, 64x64 each
    const int m0 = blockIdx.x * 128;
    const int lr = lane & 15;
    const int hi = lane >> 4;
    const int lk = hi * 8;

    // stage A (CSR-linear) and B, full K=64
#pragma unroll
    for (int i = 0; i < 4; ++i) {
        int c = tid + 256 * i;  // 0..1023
        int row = c >> 3, ko = (c & 7) * 8;
        int gm = m0 + row;
        uint4 t = make_uint4(0u, 0u, 0u, 0u);
        if (gm < M) t = *(const uint4*)(eab + (size_t)gm * EDGE_C + ko);
        *(uint4*)&As[row * 72 + ko] = t;
        *(uint4*)&Bs[row * 72 + ko] = *(const uint4*)(Wt + (size_t)row * EDGE_C + ko);
    }
    __syncthreads();

    f32x4 acc[4][4] = {};
#pragma unroll
    for (int ks = 0; ks < 2; ++ks) {
        s16x8 a[4], b[4];
#pragma unroll
        for (int mf = 0; mf < 4; ++mf)
            a[mf] = *(const s16x8*)&As[(wm * 64 + mf * 16 + lr) * 72 + ks * 32 + lk];
#pragma unroll
        for (int nf = 0; nf < 4; ++nf)
            b[nf] = *(const s16x8*)&Bs[(wn * 64 + nf * 16 + lr) * 72 + ks * 32 + lk];
#pragma unroll
        for (int mf = 0; mf < 4; ++mf)
#pragma unroll
            for (int nf = 0; nf < 4; ++nf)
                acc[mf][nf] =
                    __builtin_amdgcn_mfma_f32_16x16x32_bf16(a[mf], b[nf], acc[mf][nf], 0, 0, 0);
    }
    __syncthreads();  // done with As/Bs

    // acc (+bias) -> LDS bf16, Cs[row][col], stride 136
#pragma unroll
    for (int nf = 0; nf < 4; ++nf) {
        int col = wn * 64 + nf * 16 + lr;
        float bcol = bias[col];
#pragma unroll
        for (int mf = 0; mf < 4; ++mf)
#pragma unroll
            for (int r = 0; r < 4; ++r) {
                int row = wm * 64 + mf * 16 + hi * 4 + r;
                lds[row * 136 + col] = f2bf(acc[mf][nf][r] + bcol);
            }
    }
    __syncthreads();

    // output: 16 threads per row, uint4 per thread per step -> coalesced
#pragma unroll
    for (int i = 0; i < 8; ++i) {
        int c = tid + 256 * i;  // 0..2047
        int row = c >> 4, ch = (c & 15) * 8;
        int gm = m0 + row;
        if (gm >= M) continue;
        uint4 cv = *(const uint4*)&lds[row * 136 + ch];
        uint4 hv = *(const uint4*)(hb + (size_t)src_csr[gm] * HID + ch);
        const u32 ci[4] = {cv.x, cv.y, cv.z, cv.w};
        const u32 hi4[4] = {hv.x, hv.y, hv.z, hv.w};
        u32 oo[4];
#pragma unroll
        for (int q = 0; q < 4; ++q) {
            float c0 = bf2f((u16)ci[q]) + bf2f((u16)hi4[q]);
            float c1 = bf2f((u16)(ci[q] >> 16)) + bf2f((u16)(hi4[q] >> 16));
            c0 = fmaxf(c0, 0.f) + 1e-7f;
            c1 = fmaxf(c1, 0.f) + 1e-7f;
            oo[q] = pack2(f2bf(c0), f2bf(c1));
        }
        *(uint4*)(msg + (size_t)gm * HID + ch) = make_uint4(oo[0], oo[1], oo[2], oo[3]);
    }
}

// ---------------- bf16 MFMA GEMM (node GEMMs): C[M,N] = A[M,K] @ Bt[N,K]^T + bias ----------------
// ASRC: 0 = A bf16; 1 = A f32 (convert); 2 = A f32 with relu(a*scale[k]+shift[k])
// EPI:  0 = store f32 Cf[M,N];  3 = store bf16 Cb[M,N]
template <int ASRC, int EPI>
__global__ __launch_bounds__(256) void mfma_gemm(
    const void* __restrict__ Av, const u16* __restrict__ Bt,
    const float* __restrict__ bias, float* __restrict__ Cf, u16* __restrict__ Cb,
    int M, int N, int K,
    const float* __restrict__ aScale, const float* __restrict__ aShift) {
    __shared__ u16 As[128][40];
    __shared__ u16 Bs[64][40];
    const int tid = threadIdx.x;
    const int lane = tid & 63;
    const int wid = tid >> 6;
    const int wm = wid >> 1, wn = wid & 1;
    const int m0 = blockIdx.x * 128;
    const int n0 = blockIdx.y * 64;
    const int lr = lane & 15;
    const int lk = (lane >> 4) * 8;

    f32x4 acc[4][2] = {};

    for (int k0 = 0; k0 < K; k0 += 32) {
#pragma unroll
        for (int it = 0; it < 2; ++it) {
            int c = tid + 256 * it;
            int row = c >> 2, ko = (c & 3) * 8;
            int gm = m0 + row;
            uint4 t = make_uint4(0u, 0u, 0u, 0u);
            if (ASRC == 0) {
                if (gm < M) t = *(const uint4*)((const u16*)Av + (size_t)gm * K + k0 + ko);
            } else {
                float v[8] = {};
                if (gm < M) {
                    const float* ap = (const float*)Av + (size_t)gm * K + k0 + ko;
                    *(float4*)&v[0] = *(const float4*)ap;
                    *(float4*)&v[4] = *(const float4*)(ap + 4);
                }
                if (ASRC == 2) {
#pragma unroll
                    for (int j = 0; j < 8; ++j) {
                        int kk = k0 + ko + j;
                        v[j] = fmaxf(fmaf(v[j], aScale[kk], aShift[kk]), 0.f);
                    }
                }
                t.x = pack2(f2bf(v[0]), f2bf(v[1]));
                t.y = pack2(f2bf(v[2]), f2bf(v[3]));
                t.z = pack2(f2bf(v[4]), f2bf(v[5]));
                t.w = pack2(f2bf(v[6]), f2bf(v[7]));
            }
            *(uint4*)&As[row][ko] = t;
        }
        {
            int row = tid >> 2, ko = (tid & 3) * 8;
            *(uint4*)&Bs[row][ko] = *(const uint4*)(Bt + (size_t)(n0 + row) * K + k0 + ko);
        }
        __syncthreads();
        s16x8 a[4], b[2];
#pragma unroll
        for (int mf = 0; mf < 4; ++mf) a[mf] = *(const s16x8*)&As[wm * 64 + mf * 16 + lr][lk];
#pragma unroll
        for (int nf = 0; nf < 2; ++nf) b[nf] = *(const s16x8*)&Bs[wn * 32 + nf * 16 + lr][lk];
#pragma unroll
        for (int mf = 0; mf < 4; ++mf)
#pragma unroll
            for (int nf = 0; nf < 2; ++nf)
                acc[mf][nf] =
                    __builtin_amdgcn_mfma_f32_16x16x32_bf16(a[mf], b[nf], acc[mf][nf], 0, 0, 0);
        __syncthreads();
    }

#pragma unroll
    for (int nf = 0; nf < 2; ++nf) {
        int col = n0 + wn * 32 + nf * 16 + lr;
        float bcol = bias[col];
#pragma unroll
        for (int mf = 0; mf < 4; ++mf) {
#pragma unroll
            for (int r = 0; r < 4; ++r) {
                int gm = m0 + wm * 64 + mf * 16 + (lane >> 4) * 4 + r;
                if (gm >= M) continue;
                float v = acc[mf][nf][r] + bcol;
                if (EPI == 0) {
                    Cf[(size_t)gm * N + col] = v;
                } else {
                    Cb[(size_t)gm * N + col] = f2bf(v);
                }
            }
        }
    }
}

// ---------------- softmax aggregation (online, wave/node) + y = h + agg (bf16) ----------------
__global__ __launch_bounds__(256) void agg_y_kernel(const u16* __restrict__ msg,
                                                    const int* __restrict__ row_ptr,
                                                    const u16* __restrict__ hb,
                                                    u16* __restrict__ y, int nnodes) {
    int w = threadIdx.x >> 6;
    int lane = threadIdx.x & 63;
    int node = blockIdx.x * 4 + w;
    if (node >= nnodes) return;
    int beg = row_ptr[node], end = row_ptr[node + 1];
    float m0 = -INFINITY, m1 = -INFINITY;
    float d0 = 0.f, d1 = 0.f, s0 = 0.f, s1 = 0.f;
    const u16* p = msg + (size_t)beg * HID + lane * 2;
    for (int e = beg; e < end; ++e, p += HID) {
        u32 u = *(const u32*)p;
        float vx = bf2f((u16)u), vy = bf2f((u16)(u >> 16));
        float nm0 = fmaxf(m0, vx);
        float sc0 = __expf(m0 - nm0);
        float e0 = __expf(vx - nm0);
        d0 = d0 * sc0 + e0;
        s0 = fmaf(vx, e0, s0 * sc0);
        m0 = nm0;
        float nm1 = fmaxf(m1, vy);
        float sc1 = __expf(m1 - nm1);
        float e1 = __expf(vy - nm1);
        d1 = d1 * sc1 + e1;
        s1 = fmaf(vy, e1, s1 * sc1);
        m1 = nm1;
    }
    float a0 = s0 / (d0 + 1e-16f);
    float a1 = s1 / (d1 + 1e-16f);
    u32 hu = *(const u32*)(hb + (size_t)node * HID + lane * 2);
    float o0 = bf2f((u16)hu) + a0;
    float o1 = bf2f((u16)(hu >> 16)) + a1;
    *(u32*)(y + (size_t)node * HID + lane * 2) = pack2(f2bf(o0), f2bf(o1));
}

// ---------------- BatchNorm stats (two-stage, no atomics) ----------------
__global__ __launch_bounds__(256) void bn_stage1(const float* __restrict__ X, int M, int C,
                                                 float* __restrict__ part) {
    int col = threadIdx.x % C;
    int sub = threadIdx.x / C;
    int R = 256 / C;
    int rows_per_block = (M + gridDim.x - 1) / gridDim.x;
    int r0 = blockIdx.x * rows_per_block;
    int r1 = min(M, r0 + rows_per_block);
    float s = 0.f, q = 0.f;
    for (int r = r0 + sub; r < r1; r += R) {
        float v = X[(size_t)r * C + col];
        s += v;
        q = fmaf(v, v, q);
    }
    __shared__ float ls[256], lq[256];
    ls[threadIdx.x] = s;
    lq[threadIdx.x] = q;
    __syncthreads();
    if (sub == 0) {
        for (int k = 1; k < R; k++) {
            s += ls[col + k * C];
            q += lq[col + k * C];
        }
        part[(size_t)blockIdx.x * C + col] = s;
        part[(size_t)(gridDim.x + blockIdx.x) * C + col] = q;
    }
}

__global__ void bn_stage2(const float* __restrict__ part, int NB, int C, int M,
                          const float* __restrict__ g, const float* __restrict__ b,
                          float* __restrict__ scale, float* __restrict__ shift) {
    int col = threadIdx.x;
    if (col >= C) return;
    float s = 0.f, q = 0.f;
    for (int k = 0; k < NB; k++) {
        s += part[(size_t)k * C + col];
        q += part[(size_t)(NB + k) * C + col];
    }
    float inv = 1.f / (float)M;
    float mu = s * inv;
    float var = fmaf(q, inv, -mu * mu);
    float sc = g[col] * rsqrtf(var + 1e-5f);
    scale[col] = sc;
    shift[col] = b[col] - mu * sc;
}

// ---------------- h update: inter block + bf16 copy for next layer's gather ----------------
__global__ void update_kernel(const float* __restrict__ graw, const float* __restrict__ scale,
                              const float* __restrict__ shift, const float* __restrict__ prev,
                              float* __restrict__ out, u16* __restrict__ hb, int total) {
    int i = blockIdx.x * 256 + threadIdx.x;
    if (i >= total) return;
    int node = i >> 7;
    int c = i & 127;
    float v = fmaxf(fmaf(graw[i], scale[c], shift[c]), 0.f);
    if (prev) v += prev[(size_t)node * (LAYERS * HID) + c];
    out[(size_t)node * (LAYERS * HID) + c] = v;
    hb[i] = f2bf(v);
}

// ---------------- prediction head ----------------
__global__ __launch_bounds__(256) void pred_kernel(const float* __restrict__ inter,
                                                   const float* __restrict__ W,
                                                   const float* __restrict__ b,
                                                   float* __restrict__ out, int nnodes) {
    __shared__ float ws[LAYERS * HID * TASKS];
    for (int i = threadIdx.x; i < LAYERS * HID * TASKS; i += 256) ws[i] = W[i];
    __syncthreads();
    int t = threadIdx.x & 7;
    int nl = threadIdx.x >> 3;
    int node = blockIdx.x * 32 + nl;
    if (node >= nnodes) return;
    const float* row = inter + (size_t)node * (LAYERS * HID);
    float acc = b[t];
    for (int k = 0; k < LAYERS * HID; k += 4) {
        float4 a = *(const float4*)(row + k);
        acc = fmaf(a.x, ws[(k + 0) * TASKS + t], acc);
        acc = fmaf(a.y, ws[(k + 1) * TASKS + t], acc);
        acc = fmaf(a.z, ws[(k + 2) * TASKS + t], acc);
        acc = fmaf(a.w, ws[(k + 3) * TASKS + t], acc);
    }
    out[(size_t)node * TASKS + t] = acc;
}

// ---------------- launch ----------------
extern "C" void kernel_launch(void* const* d_in, const int* in_sizes, int n_in,
                              void* d_out, int out_size, void* d_ws, size_t ws_size,
                              hipStream_t stream) {
    const float* x = (const float*)d_in[0];
    const int* ei = (const int*)d_in[1];
    const float* edge_attr = (const float*)d_in[2];
    const float* enc_W = (const float*)d_in[3];
    const float* enc_b = (const float*)d_in[4];
    const float* leW = (const float*)d_in[5];
    const float* leb = (const float*)d_in[6];
    const float* W1 = (const float*)d_in[7];
    const float* b1 = (const float*)d_in[8];
    const float* ng = (const float*)d_in[9];
    const float* nb = (const float*)d_in[10];
    const float* W2 = (const float*)d_in[11];
    const float* b2 = (const float*)d_in[12];
    const float* og = (const float*)d_in[13];
    const float* ob = (const float*)d_in[14];
    const float* pW = (const float*)d_in[15];
    const float* pb = (const float*)d_in[16];
    float* out = (float*)d_out;

    const int E = in_sizes[1] / 2;
    const int* src = ei;
    const int* dst = ei + E;

    char* w = (char*)d_ws;
    size_t off = 0;
    auto alloc = [&](size_t bytes) {
        void* p = w + off;
        off = (off + bytes + 255) & ~(size_t)255;
        return p;
    };
    float* inter = (float*)alloc((size_t)NN * LAYERS * HID * 4);  // 76.8 MB
    u16* msg = (u16*)alloc((size_t)NE * HID * 2);                 // 128 MB
    u16* eab = (u16*)alloc((size_t)NE * EDGE_C * 2);              // 64 MB (CSR order)
    u16* hb = (u16*)alloc((size_t)NN * HID * 2);
    u16* yb = (u16*)alloc((size_t)NN * HID * 2);
    float* z = (float*)alloc((size_t)NN * 2 * HID * 4);
    float* graw = (float*)alloc((size_t)NN * HID * 4);
    u16* encWt = (u16*)alloc((size_t)IN_C * HID * 2);
    u16* leWt = (u16*)alloc((size_t)LAYERS * HID * EDGE_C * 2);
    u16* W1t = (u16*)alloc((size_t)LAYERS * 2 * HID * HID * 2);
    u16* W2t = (u16*)alloc((size_t)LAYERS * HID * 2 * HID * 2);
    int* row_ptr = (int*)alloc((size_t)(NN + 1) * 4);
    int* cnt = (int*)alloc((size_t)NN * 4);
    int* pos = (int*)alloc((size_t)NE * 4);
    int* eperm = (int*)alloc((size_t)NE * 4);
    int* src_csr = (int*)alloc((size_t)NE * 4);
    int* bsum = (int*)alloc((size_t)256 * 4);
    int* boff = (int*)alloc((size_t)256 * 4);
    float* part = (float*)alloc((size_t)2 * 256 * 256 * 4);
    float* bnsc = (float*)alloc(256 * 4);
    float* bnsh = (float*)alloc(256 * 4);
    float* bnsc2 = (float*)alloc(128 * 4);
    float* bnsh2 = (float*)alloc(128 * 4);
    if (off > ws_size) return;  // insufficient workspace: fail loudly, don't corrupt

    const int NB_SCAN = (NN + 255) / 256;  // 196

    // ---- CSR build ----
    zero_i32_kernel<<<(NN + 255) / 256, 256, 0, stream>>>(cnt, NN);
    hist_kernel<<<(E + 255) / 256, 256, 0, stream>>>(dst, cnt, E);
    scan1_kernel<<<NB_SCAN, 256, 0, stream>>>(cnt, row_ptr, bsum, NN);
    scan2_kernel<<<1, 256, 0, stream>>>(bsum, boff, NB_SCAN, row_ptr + NN);
    scan3_kernel<<<NB_SCAN, 256, 0, stream>>>(row_ptr, boff, NN);
    zero_i32_kernel<<<(NN + 255) / 256, 256, 0, stream>>>(cnt, NN);
    pos_kernel<<<(E + 255) / 256, 256, 0, stream>>>(dst, row_ptr, cnt, pos, E);
    eperm_kernel<<<(E + 255) / 256, 256, 0, stream>>>(pos, eperm, E);
    gatherconv_kernel<<<(E * 16 + 255) / 256, 256, 0, stream>>>(edge_attr, eperm, src,
                                                                eab, src_csr, E);

    // ---- weight prep ----
    wconv_kernel<<<(IN_C * HID + 255) / 256, 256, 0, stream>>>(enc_W, encWt, IN_C, HID);
    for (int l = 0; l < LAYERS; l++) {
        wconv_kernel<<<(EDGE_C * HID + 255) / 256, 256, 0, stream>>>(
            leW + (size_t)l * EDGE_C * HID, leWt + (size_t)l * HID * EDGE_C, EDGE_C, HID);
        wconv_kernel<<<(HID * 2 * HID + 255) / 256, 256, 0, stream>>>(
            W1 + (size_t)l * HID * 2 * HID, W1t + (size_t)l * 2 * HID * HID, HID, 2 * HID);
        wconv_kernel<<<(2 * HID * HID + 255) / 256, 256, 0, stream>>>(
            W2 + (size_t)l * 2 * HID * HID, W2t + (size_t)l * HID * 2 * HID, 2 * HID, HID);
    }

    // ---- encoder: hb = bf16(x @ enc_W + enc_b) ----
    {
        dim3 grid((NN + 127) / 128, HID / 64);
        mfma_gemm<1, 3><<<grid, 256, 0, stream>>>(x, encWt, enc_b, nullptr, hb, NN, HID, IN_C,
                                                  nullptr, nullptr);
    }

    for (int l = 0; l < LAYERS; l++) {
        // msg (CSR-linear) = bf16(relu(eab@leW + leb + hb[src_csr]) + 1e-7)
        edge_msg_kernel<<<(E + 127) / 128, 256, 0, stream>>>(
            eab, leWt + (size_t)l * HID * EDGE_C, leb + (size_t)l * HID, src_csr, hb, msg, E);
        // softmax aggregation + y = h + agg (bf16)
        agg_y_kernel<<<(NN + 3) / 4, 256, 0, stream>>>(msg, row_ptr, hb, yb, NN);
        // z = y @ W1 + b1 (f32 out)
        {
            dim3 grid((NN + 127) / 128, (2 * HID) / 64);
            mfma_gemm<0, 0><<<grid, 256, 0, stream>>>(
                yb, W1t + (size_t)l * 2 * HID * HID, b1 + (size_t)l * 2 * HID, z, nullptr,
                NN, 2 * HID, HID, nullptr, nullptr);
        }
        bn_stage1<<<256, 256, 0, stream>>>(z, NN, 2 * HID, part);
        bn_stage2<<<1, 256, 0, stream>>>(part, 256, 2 * HID, NN,
                                         ng + (size_t)l * 2 * HID, nb + (size_t)l * 2 * HID,
                                         bnsc, bnsh);
        // graw = relu(bn(z)) @ W2 + b2 (BN+relu fused into A staging)
        {
            dim3 grid((NN + 127) / 128, HID / 64);
            mfma_gemm<2, 0><<<grid, 256, 0, stream>>>(
                z, W2t + (size_t)l * HID * 2 * HID, b2 + (size_t)l * HID, graw, nullptr,
                NN, HID, 2 * HID, bnsc, bnsh);
        }
        bn_stage1<<<256, 256, 0, stream>>>(graw, NN, HID, part);
        bn_stage2<<<1, 128, 0, stream>>>(part, 256, HID, NN,
                                         og + (size_t)l * HID, ob + (size_t)l * HID,
                                         bnsc2, bnsh2);
        {
            const float* prev = (l == 0) ? nullptr : (inter + (size_t)(l - 1) * HID);
            update_kernel<<<(NN * HID + 255) / 256, 256, 0, stream>>>(
                graw, bnsc2, bnsh2, prev, inter + (size_t)l * HID, hb, NN * HID);
        }
    }

    pred_kernel<<<(NN + 31) / 32, 256, 0, stream>>>(inter, pW, pb, out, NN);
    (void)out_size;
    (void)n_in;
}

// Round 5
// 969.393 us; speedup vs baseline: 2.1193x; 1.5606x over previous
//
#include <hip/hip_runtime.h>
#include <math.h>

#define NN 50000
#define NE 500000
#define HID 128
#define EDGE_C 64
#define IN_C 128
#define TASKS 8
#define LAYERS 3

typedef unsigned short u16;
typedef unsigned int u32;
typedef __attribute__((ext_vector_type(8))) short s16x8;
typedef __attribute__((ext_vector_type(4))) float f32x4;

__device__ __forceinline__ u16 f2bf(float f) {
    u32 u = __float_as_uint(f);
    u += 0x7fffu + ((u >> 16) & 1u);  // RNE
    return (u16)(u >> 16);
}
__device__ __forceinline__ float bf2f(u16 h) {
    return __uint_as_float(((u32)h) << 16);
}
__device__ __forceinline__ u32 pack2(u16 lo, u16 hi) { return (u32)lo | ((u32)hi << 16); }

// ---------------- small utility kernels ----------------
__global__ void zero_i32_kernel(int* p, int n) {
    int i = blockIdx.x * 256 + threadIdx.x;
    if (i < n) p[i] = 0;
}
__global__ void zero_f32_kernel(float* p, int n) {
    int i = blockIdx.x * 256 + threadIdx.x;
    if (i < n) p[i] = 0.f;
}

__global__ void hist_kernel(const int* __restrict__ dst, int* __restrict__ cnt, int E) {
    int e = blockIdx.x * 256 + threadIdx.x;
    if (e < E) atomicAdd(&cnt[dst[e]], 1);
}

// hierarchical exclusive scan
__global__ __launch_bounds__(256) void scan1_kernel(const int* __restrict__ cnt,
                                                    int* __restrict__ row_ptr,
                                                    int* __restrict__ bsum, int n) {
    __shared__ int buf[256];
    int i = blockIdx.x * 256 + threadIdx.x;
    int v = (i < n) ? cnt[i] : 0;
    buf[threadIdx.x] = v;
    __syncthreads();
    for (int off = 1; off < 256; off <<= 1) {
        int t = ((int)threadIdx.x >= off) ? buf[threadIdx.x - off] : 0;
        __syncthreads();
        buf[threadIdx.x] += t;
        __syncthreads();
    }
    if (i < n) row_ptr[i] = buf[threadIdx.x] - v;
    if (threadIdx.x == 255) bsum[blockIdx.x] = buf[255];
}

__global__ __launch_bounds__(256) void scan2_kernel(const int* __restrict__ bsum,
                                                    int* __restrict__ boff, int nb,
                                                    int* __restrict__ row_end) {
    __shared__ int buf[256];
    int v = ((int)threadIdx.x < nb) ? bsum[threadIdx.x] : 0;
    buf[threadIdx.x] = v;
    __syncthreads();
    for (int off = 1; off < 256; off <<= 1) {
        int t = ((int)threadIdx.x >= off) ? buf[threadIdx.x - off] : 0;
        __syncthreads();
        buf[threadIdx.x] += t;
        __syncthreads();
    }
    if ((int)threadIdx.x < nb) boff[threadIdx.x] = buf[threadIdx.x] - v;
    if ((int)threadIdx.x == nb - 1) *row_end = buf[threadIdx.x];
}

__global__ void scan3_kernel(int* __restrict__ row_ptr, const int* __restrict__ boff, int n) {
    int i = blockIdx.x * 256 + threadIdx.x;
    if (i < n) row_ptr[i] += boff[blockIdx.x];
}

__global__ void pos_kernel(const int* __restrict__ dst, const int* __restrict__ row_ptr,
                           int* __restrict__ cnt, int* __restrict__ pos, int E) {
    int e = blockIdx.x * 256 + threadIdx.x;
    if (e < E) {
        int d = dst[e];
        int off = atomicAdd(&cnt[d], 1);
        pos[e] = row_ptr[d] + off;
    }
}

__global__ void eperm_kernel(const int* __restrict__ pos, int* __restrict__ eperm, int E) {
    int e = blockIdx.x * 256 + threadIdx.x;
    if (e < E) eperm[pos[e]] = e;
}

// gather edge_attr into CSR order + convert to bf16; also src_csr. 16 threads/slot.
__global__ void gatherconv_kernel(const float* __restrict__ edge_attr,
                                  const int* __restrict__ eperm, const int* __restrict__ src,
                                  u16* __restrict__ eab, int* __restrict__ src_csr, int E) {
    int t = blockIdx.x * 256 + threadIdx.x;
    if (t >= E * 16) return;
    int slot = t >> 4, j = t & 15;
    int e = eperm[slot];
    float4 v = *(const float4*)(edge_attr + (size_t)e * EDGE_C + j * 4);
    u16 o[4] = {f2bf(v.x), f2bf(v.y), f2bf(v.z), f2bf(v.w)};
    *(uint2*)(eab + (size_t)slot * EDGE_C + j * 4) = *(uint2*)o;
    if (j == 0) src_csr[slot] = src[e];
}

// ---------------- weight transpose+convert W[K][N] f32 -> Bt[N][K] bf16 ----------------
__global__ void wconv_kernel(const float* __restrict__ W, u16* __restrict__ Bt, int K, int N) {
    int i = blockIdx.x * 256 + threadIdx.x;
    if (i >= K * N) return;
    int n = i / K, k = i % K;
    Bt[i] = f2bf(W[(size_t)k * N + n]);
}

// ---------------- fused GENConv edge pipeline ----------------
// One block per 8 consecutive destination nodes (edges contiguous in CSR order).
// Per 64-edge chunk: MFMA (eab @ leW) -> LDS bf16 msgs (+bias) -> += hb[src], relu, +eps
// -> per-thread online softmax (register state, node x 4 cols) -> y = hb + s/d at the end.
__global__ __launch_bounds__(256) void genconv_kernel(
    const u16* __restrict__ eab, const u16* __restrict__ Wt, const float* __restrict__ bias,
    const int* __restrict__ src_csr, const int* __restrict__ row_ptr,
    const u16* __restrict__ hb, u16* __restrict__ yb, int nnodes, int E) {
    __shared__ u16 Wl[128 * 72];    // 18 KB
    __shared__ u16 Asl[64 * 72];    // 9 KB
    __shared__ u16 msgs[64 * 136];  // 17 KB
    __shared__ int rp[9];
    const int tid = threadIdx.x;
    const int lane = tid & 63;
    const int wn = tid >> 6;  // wave id = col block (4 waves x 32 cols)
    const int lr = lane & 15;
    const int hi = lane >> 4;
    const int lk = hi * 8;
    const int n0 = blockIdx.x * 8;

    if (tid < 9) rp[tid] = row_ptr[min(n0 + tid, nnodes)];
    // stage leW (128 cols x 64 k)
#pragma unroll
    for (int i = 0; i < 4; ++i) {
        int c = tid + 256 * i;
        int row = c >> 3, ko = (c & 7) * 8;
        *(uint4*)&Wl[row * 72 + ko] = *(const uint4*)(Wt + (size_t)row * EDGE_C + ko);
    }
    __syncthreads();

    const int beg = rp[0], end = rp[8];
    const int g = tid >> 5;            // node within group (0..7)
    const int colq = (tid & 31) * 4;   // 4 cols per thread
    float m4[4], d4[4], s4[4];
#pragma unroll
    for (int j = 0; j < 4; ++j) { m4[j] = -INFINITY; d4[j] = 0.f; s4[j] = 0.f; }

    for (int lo = beg; lo < end; lo += 64) {
        int sz = min(64, end - lo);
        __syncthreads();  // previous chunk's softmax reads done before restaging
        // stage edge rows
#pragma unroll
        for (int i = 0; i < 2; ++i) {
            int c = tid + 256 * i;
            int row = c >> 3, ko = (c & 7) * 8;
            uint4 t = make_uint4(0u, 0u, 0u, 0u);
            if (row < sz) t = *(const uint4*)(eab + (size_t)(lo + row) * EDGE_C + ko);
            *(uint4*)&Asl[row * 72 + ko] = t;
        }
        __syncthreads();
        // MFMA: 64 rows x 128 cols (wave wn owns cols wn*32..+32)
        f32x4 acc[4][2] = {};
#pragma unroll
        for (int ks = 0; ks < 2; ++ks) {
            s16x8 a[4], b[2];
#pragma unroll
            for (int mf = 0; mf < 4; ++mf)
                a[mf] = *(const s16x8*)&Asl[(mf * 16 + lr) * 72 + ks * 32 + lk];
#pragma unroll
            for (int nf = 0; nf < 2; ++nf)
                b[nf] = *(const s16x8*)&Wl[(wn * 32 + nf * 16 + lr) * 72 + ks * 32 + lk];
#pragma unroll
            for (int mf = 0; mf < 4; ++mf)
#pragma unroll
                for (int nf = 0; nf < 2; ++nf)
                    acc[mf][nf] =
                        __builtin_amdgcn_mfma_f32_16x16x32_bf16(a[mf], b[nf], acc[mf][nf], 0, 0, 0);
        }
        // acc (+bias) -> msgs
#pragma unroll
        for (int nf = 0; nf < 2; ++nf) {
            int col = wn * 32 + nf * 16 + lr;
            float bcol = bias[col];
#pragma unroll
            for (int mf = 0; mf < 4; ++mf)
#pragma unroll
                for (int r = 0; r < 4; ++r) {
                    int row = mf * 16 + hi * 4 + r;
                    msgs[row * 136 + col] = f2bf(acc[mf][nf][r] + bcol);
                }
        }
        __syncthreads();
        // += hb[src], relu, +eps (vectorized, 16 threads/row)
#pragma unroll
        for (int i = 0; i < 4; ++i) {
            int c = tid + 256 * i;
            int row = c >> 4, ch = (c & 15) * 8;
            if (row < sz) {
                int s = src_csr[lo + row];
                uint4 hv = *(const uint4*)(hb + (size_t)s * HID + ch);
                uint4 cv = *(const uint4*)&msgs[row * 136 + ch];
                const u32 ci[4] = {cv.x, cv.y, cv.z, cv.w};
                const u32 hh[4] = {hv.x, hv.y, hv.z, hv.w};
                u32 oo[4];
#pragma unroll
                for (int q = 0; q < 4; ++q) {
                    float c0 = fmaxf(bf2f((u16)ci[q]) + bf2f((u16)hh[q]), 0.f) + 1e-7f;
                    float c1 = fmaxf(bf2f((u16)(ci[q] >> 16)) + bf2f((u16)(hh[q] >> 16)), 0.f) + 1e-7f;
                    oo[q] = pack2(f2bf(c0), f2bf(c1));
                }
                *(uint4*)&msgs[row * 136 + ch] = make_uint4(oo[0], oo[1], oo[2], oo[3]);
            }
        }
        __syncthreads();
        // online softmax update for this thread's (node, 4 cols)
        int r0 = max(rp[g], lo) - lo;
        int r1 = min(rp[g + 1], lo + sz) - lo;
        for (int r = r0; r < r1; ++r) {
            u32 a0 = *(const u32*)&msgs[r * 136 + colq];
            u32 a1 = *(const u32*)&msgs[r * 136 + colq + 2];
            float v[4] = {bf2f((u16)a0), bf2f((u16)(a0 >> 16)), bf2f((u16)a1),
                          bf2f((u16)(a1 >> 16))};
#pragma unroll
            for (int j = 0; j < 4; ++j) {
                float nm = fmaxf(m4[j], v[j]);
                float sc = __expf(m4[j] - nm);
                float ee = __expf(v[j] - nm);
                d4[j] = d4[j] * sc + ee;
                s4[j] = fmaf(v[j], ee, s4[j] * sc);
                m4[j] = nm;
            }
        }
    }

    // y = hb + agg
    int node = n0 + g;
    if (node < nnodes) {
        u32 h0 = *(const u32*)(hb + (size_t)node * HID + colq);
        u32 h1 = *(const u32*)(hb + (size_t)node * HID + colq + 2);
        float o0 = bf2f((u16)h0) + s4[0] / (d4[0] + 1e-16f);
        float o1 = bf2f((u16)(h0 >> 16)) + s4[1] / (d4[1] + 1e-16f);
        float o2 = bf2f((u16)h1) + s4[2] / (d4[2] + 1e-16f);
        float o3 = bf2f((u16)(h1 >> 16)) + s4[3] / (d4[3] + 1e-16f);
        uint2 o = make_uint2(pack2(f2bf(o0), f2bf(o1)), pack2(f2bf(o2), f2bf(o3)));
        *(uint2*)(yb + (size_t)node * HID + colq) = o;
    }
    (void)E;
}

// ---------------- bf16 MFMA GEMM: C[M,N] = A[M,K] @ Bt[N,K]^T + bias ----------------
// ASRC: 0 = A bf16; 1 = A f32 (convert); 3 = A bf16 with relu(a*scale[k]+shift[k])
// EPI:  0 = store f32 Cf[M,N];  3 = store bf16 Cb[M,N]
// SUMS: accumulate per-column sum/sumsq of output into sumP/sqP (for fused BN stats)
template <int ASRC, int EPI, bool SUMS>
__global__ __launch_bounds__(256) void mfma_gemm(
    const void* __restrict__ Av, const u16* __restrict__ Bt,
    const float* __restrict__ bias, float* __restrict__ Cf, u16* __restrict__ Cb,
    int M, int N, int K,
    const float* __restrict__ aScale, const float* __restrict__ aShift,
    float* __restrict__ sumP, float* __restrict__ sqP) {
    __shared__ u16 As[128][40];
    __shared__ u16 Bs[64][40];
    const int tid = threadIdx.x;
    const int lane = tid & 63;
    const int wid = tid >> 6;
    const int wm = wid >> 1, wn = wid & 1;
    const int m0 = blockIdx.x * 128;
    const int n0 = blockIdx.y * 64;
    const int lr = lane & 15;
    const int hi = lane >> 4;
    const int lk = hi * 8;

    f32x4 acc[4][2] = {};

    for (int k0 = 0; k0 < K; k0 += 32) {
#pragma unroll
        for (int it = 0; it < 2; ++it) {
            int c = tid + 256 * it;
            int row = c >> 2, ko = (c & 3) * 8;
            int gm = m0 + row;
            uint4 t = make_uint4(0u, 0u, 0u, 0u);
            if (ASRC == 0) {
                if (gm < M) t = *(const uint4*)((const u16*)Av + (size_t)gm * K + k0 + ko);
            } else if (ASRC == 1) {
                float v[8] = {};
                if (gm < M) {
                    const float* ap = (const float*)Av + (size_t)gm * K + k0 + ko;
                    *(float4*)&v[0] = *(const float4*)ap;
                    *(float4*)&v[4] = *(const float4*)(ap + 4);
                }
                t.x = pack2(f2bf(v[0]), f2bf(v[1]));
                t.y = pack2(f2bf(v[2]), f2bf(v[3]));
                t.z = pack2(f2bf(v[4]), f2bf(v[5]));
                t.w = pack2(f2bf(v[6]), f2bf(v[7]));
            } else {  // ASRC == 3: bf16 in + per-k BN transform + relu
                uint4 raw = make_uint4(0u, 0u, 0u, 0u);
                if (gm < M) raw = *(const uint4*)((const u16*)Av + (size_t)gm * K + k0 + ko);
                const u32 rr[4] = {raw.x, raw.y, raw.z, raw.w};
                u32 ot[4];
#pragma unroll
                for (int q = 0; q < 4; ++q) {
                    int kk = k0 + ko + q * 2;
                    float v0 = fmaxf(fmaf(bf2f((u16)rr[q]), aScale[kk], aShift[kk]), 0.f);
                    float v1 = fmaxf(fmaf(bf2f((u16)(rr[q] >> 16)), aScale[kk + 1], aShift[kk + 1]), 0.f);
                    ot[q] = pack2(f2bf(v0), f2bf(v1));
                }
                t = make_uint4(ot[0], ot[1], ot[2], ot[3]);
            }
            *(uint4*)&As[row][ko] = t;
        }
        {
            int row = tid >> 2, ko = (tid & 3) * 8;
            *(uint4*)&Bs[row][ko] = *(const uint4*)(Bt + (size_t)(n0 + row) * K + k0 + ko);
        }
        __syncthreads();
        s16x8 a[4], b[2];
#pragma unroll
        for (int mf = 0; mf < 4; ++mf) a[mf] = *(const s16x8*)&As[wm * 64 + mf * 16 + lr][lk];
#pragma unroll
        for (int nf = 0; nf < 2; ++nf) b[nf] = *(const s16x8*)&Bs[wn * 32 + nf * 16 + lr][lk];
#pragma unroll
        for (int mf = 0; mf < 4; ++mf)
#pragma unroll
            for (int nf = 0; nf < 2; ++nf)
                acc[mf][nf] =
                    __builtin_amdgcn_mfma_f32_16x16x32_bf16(a[mf], b[nf], acc[mf][nf], 0, 0, 0);
        __syncthreads();
    }

    float sl[2] = {0.f, 0.f}, ql[2] = {0.f, 0.f};
#pragma unroll
    for (int nf = 0; nf < 2; ++nf) {
        int col = n0 + wn * 32 + nf * 16 + lr;
        float bcol = bias[col];
#pragma unroll
        for (int mf = 0; mf < 4; ++mf) {
#pragma unroll
            for (int r = 0; r < 4; ++r) {
                int gm = m0 + wm * 64 + mf * 16 + hi * 4 + r;
                if (gm >= M) continue;
                float v = acc[mf][nf][r] + bcol;
                if (EPI == 0) {
                    Cf[(size_t)gm * N + col] = v;
                } else {
                    Cb[(size_t)gm * N + col] = f2bf(v);
                }
                if (SUMS) {
                    sl[nf] += v;
                    ql[nf] = fmaf(v, v, ql[nf]);
                }
            }
        }
    }
    if (SUMS) {
        __syncthreads();
        float* red = (float*)&As[0][0];  // [2][8][64] = 4 KB
        int group = wm * 4 + hi;
#pragma unroll
        for (int nf = 0; nf < 2; ++nf) {
            int coll = wn * 32 + nf * 16 + lr;
            red[group * 64 + coll] = sl[nf];
            red[512 + group * 64 + coll] = ql[nf];
        }
        __syncthreads();
        if (tid < 64) {
            float s = 0.f;
#pragma unroll
            for (int gg = 0; gg < 8; ++gg) s += red[gg * 64 + tid];
            atomicAdd(&sumP[n0 + tid], s);
        } else if (tid < 128) {
            int c2 = tid - 64;
            float q = 0.f;
#pragma unroll
            for (int gg = 0; gg < 8; ++gg) q += red[512 + gg * 64 + c2];
            atomicAdd(&sqP[n0 + c2], q);
        }
    }
}

// ---------------- BN scale/shift from fused sums ----------------
__global__ void bn2_kernel(const float* __restrict__ sumP, const float* __restrict__ sqP,
                           int C, int M, const float* __restrict__ g,
                           const float* __restrict__ b, float* __restrict__ scale,
                           float* __restrict__ shift) {
    int c = threadIdx.x;
    if (c >= C) return;
    float inv = 1.f / (float)M;
    float mu = sumP[c] * inv;
    float var = fmaf(sqP[c], inv, -mu * mu);
    float sc = g[c] * rsqrtf(var + 1e-5f);
    scale[c] = sc;
    shift[c] = b[c] - mu * sc;
}

// ---------------- h update: inter block + bf16 copy for next layer's gather ----------------
__global__ void update_kernel(const float* __restrict__ graw, const float* __restrict__ scale,
                              const float* __restrict__ shift, const float* __restrict__ prev,
                              float* __restrict__ out, u16* __restrict__ hb, int total) {
    int i = blockIdx.x * 256 + threadIdx.x;
    if (i >= total) return;
    int node = i >> 7;
    int c = i & 127;
    float v = fmaxf(fmaf(graw[i], scale[c], shift[c]), 0.f);
    if (prev) v += prev[(size_t)node * (LAYERS * HID) + c];
    out[(size_t)node * (LAYERS * HID) + c] = v;
    hb[i] = f2bf(v);
}

// ---------------- prediction head ----------------
__global__ __launch_bounds__(256) void pred_kernel(const float* __restrict__ inter,
                                                   const float* __restrict__ W,
                                                   const float* __restrict__ b,
                                                   float* __restrict__ out, int nnodes) {
    __shared__ float ws[LAYERS * HID * TASKS];
    for (int i = threadIdx.x; i < LAYERS * HID * TASKS; i += 256) ws[i] = W[i];
    __syncthreads();
    int t = threadIdx.x & 7;
    int nl = threadIdx.x >> 3;
    int node = blockIdx.x * 32 + nl;
    if (node >= nnodes) return;
    const float* row = inter + (size_t)node * (LAYERS * HID);
    float acc = b[t];
    for (int k = 0; k < LAYERS * HID; k += 4) {
        float4 a = *(const float4*)(row + k);
        acc = fmaf(a.x, ws[(k + 0) * TASKS + t], acc);
        acc = fmaf(a.y, ws[(k + 1) * TASKS + t], acc);
        acc = fmaf(a.z, ws[(k + 2) * TASKS + t], acc);
        acc = fmaf(a.w, ws[(k + 3) * TASKS + t], acc);
    }
    out[(size_t)node * TASKS + t] = acc;
}

// ---------------- launch ----------------
extern "C" void kernel_launch(void* const* d_in, const int* in_sizes, int n_in,
                              void* d_out, int out_size, void* d_ws, size_t ws_size,
                              hipStream_t stream) {
    const float* x = (const float*)d_in[0];
    const int* ei = (const int*)d_in[1];
    const float* edge_attr = (const float*)d_in[2];
    const float* enc_W = (const float*)d_in[3];
    const float* enc_b = (const float*)d_in[4];
    const float* leW = (const float*)d_in[5];
    const float* leb = (const float*)d_in[6];
    const float* W1 = (const float*)d_in[7];
    const float* b1 = (const float*)d_in[8];
    const float* ng = (const float*)d_in[9];
    const float* nb = (const float*)d_in[10];
    const float* W2 = (const float*)d_in[11];
    const float* b2 = (const float*)d_in[12];
    const float* og = (const float*)d_in[13];
    const float* ob = (const float*)d_in[14];
    const float* pW = (const float*)d_in[15];
    const float* pb = (const float*)d_in[16];
    float* out = (float*)d_out;

    const int E = in_sizes[1] / 2;
    const int* src = ei;
    const int* dst = ei + E;

    char* w = (char*)d_ws;
    size_t off = 0;
    auto alloc = [&](size_t bytes) {
        void* p = w + off;
        off = (off + bytes + 255) & ~(size_t)255;
        return p;
    };
    float* inter = (float*)alloc((size_t)NN * LAYERS * HID * 4);  // 76.8 MB
    u16* eab = (u16*)alloc((size_t)NE * EDGE_C * 2);              // 64 MB (CSR order)
    u16* hb = (u16*)alloc((size_t)NN * HID * 2);
    u16* yb = (u16*)alloc((size_t)NN * HID * 2);
    u16* z = (u16*)alloc((size_t)NN * 2 * HID * 2);               // bf16 z
    float* graw = (float*)alloc((size_t)NN * HID * 4);
    u16* encWt = (u16*)alloc((size_t)IN_C * HID * 2);
    u16* leWt = (u16*)alloc((size_t)LAYERS * HID * EDGE_C * 2);
    u16* W1t = (u16*)alloc((size_t)LAYERS * 2 * HID * HID * 2);
    u16* W2t = (u16*)alloc((size_t)LAYERS * HID * 2 * HID * 2);
    int* row_ptr = (int*)alloc((size_t)(NN + 1) * 4);
    int* cnt = (int*)alloc((size_t)NN * 4);
    int* pos = (int*)alloc((size_t)NE * 4);
    int* eperm = (int*)alloc((size_t)NE * 4);
    int* src_csr = (int*)alloc((size_t)NE * 4);
    int* bsum = (int*)alloc((size_t)256 * 4);
    int* boff = (int*)alloc((size_t)256 * 4);
    float* sumZ = (float*)alloc((size_t)LAYERS * 256 * 4);
    float* sqZ = (float*)alloc((size_t)LAYERS * 256 * 4);
    float* sumG = (float*)alloc((size_t)LAYERS * 128 * 4);
    float* sqG = (float*)alloc((size_t)LAYERS * 128 * 4);
    float* bnsc = (float*)alloc(256 * 4);
    float* bnsh = (float*)alloc(256 * 4);
    float* bnsc2 = (float*)alloc(128 * 4);
    float* bnsh2 = (float*)alloc(128 * 4);
    if (off > ws_size) return;  // insufficient workspace: fail loudly, don't corrupt

    const int NB_SCAN = (NN + 255) / 256;

    // ---- CSR build ----
    zero_i32_kernel<<<(NN + 255) / 256, 256, 0, stream>>>(cnt, NN);
    hist_kernel<<<(E + 255) / 256, 256, 0, stream>>>(dst, cnt, E);
    scan1_kernel<<<NB_SCAN, 256, 0, stream>>>(cnt, row_ptr, bsum, NN);
    scan2_kernel<<<1, 256, 0, stream>>>(bsum, boff, NB_SCAN, row_ptr + NN);
    scan3_kernel<<<NB_SCAN, 256, 0, stream>>>(row_ptr, boff, NN);
    zero_i32_kernel<<<(NN + 255) / 256, 256, 0, stream>>>(cnt, NN);
    pos_kernel<<<(E + 255) / 256, 256, 0, stream>>>(dst, row_ptr, cnt, pos, E);
    eperm_kernel<<<(E + 255) / 256, 256, 0, stream>>>(pos, eperm, E);
    gatherconv_kernel<<<(E * 16 + 255) / 256, 256, 0, stream>>>(edge_attr, eperm, src,
                                                                eab, src_csr, E);
    // ---- zero BN sum accumulators ----
    zero_f32_kernel<<<9, 256, 0, stream>>>(sumZ, LAYERS * 256 * 2 + LAYERS * 128 * 2);

    // ---- weight prep ----
    wconv_kernel<<<(IN_C * HID + 255) / 256, 256, 0, stream>>>(enc_W, encWt, IN_C, HID);
    for (int l = 0; l < LAYERS; l++) {
        wconv_kernel<<<(EDGE_C * HID + 255) / 256, 256, 0, stream>>>(
            leW + (size_t)l * EDGE_C * HID, leWt + (size_t)l * HID * EDGE_C, EDGE_C, HID);
        wconv_kernel<<<(HID * 2 * HID + 255) / 256, 256, 0, stream>>>(
            W1 + (size_t)l * HID * 2 * HID, W1t + (size_t)l * 2 * HID * HID, HID, 2 * HID);
        wconv_kernel<<<(2 * HID * HID + 255) / 256, 256, 0, stream>>>(
            W2 + (size_t)l * 2 * HID * HID, W2t + (size_t)l * HID * 2 * HID, 2 * HID, HID);
    }

    // ---- encoder: hb = bf16(x @ enc_W + enc_b) ----
    {
        dim3 grid((NN + 127) / 128, HID / 64);
        mfma_gemm<1, 3, false><<<grid, 256, 0, stream>>>(
            x, encWt, enc_b, nullptr, hb, NN, HID, IN_C, nullptr, nullptr, nullptr, nullptr);
    }

    for (int l = 0; l < LAYERS; l++) {
        // fused edge GEMM + message + online softmax + y
        genconv_kernel<<<(NN + 7) / 8, 256, 0, stream>>>(
            eab, leWt + (size_t)l * HID * EDGE_C, leb + (size_t)l * HID, src_csr, row_ptr,
            hb, yb, NN, E);
        // z = y @ W1 + b1 (bf16 out, BN sums fused)
        {
            dim3 grid((NN + 127) / 128, (2 * HID) / 64);
            mfma_gemm<0, 3, true><<<grid, 256, 0, stream>>>(
                yb, W1t + (size_t)l * 2 * HID * HID, b1 + (size_t)l * 2 * HID, nullptr, z,
                NN, 2 * HID, HID, nullptr, nullptr, sumZ + l * 256, sqZ + l * 256);
        }
        bn2_kernel<<<1, 256, 0, stream>>>(sumZ + l * 256, sqZ + l * 256, 2 * HID, NN,
                                          ng + (size_t)l * 2 * HID, nb + (size_t)l * 2 * HID,
                                          bnsc, bnsh);
        // graw = relu(bn(z)) @ W2 + b2 (BN apply fused into A staging; graw BN sums fused)
        {
            dim3 grid((NN + 127) / 128, HID / 64);
            mfma_gemm<3, 0, true><<<grid, 256, 0, stream>>>(
                z, W2t + (size_t)l * HID * 2 * HID, b2 + (size_t)l * HID, graw, nullptr,
                NN, HID, 2 * HID, bnsc, bnsh, sumG + l * 128, sqG + l * 128);
        }
        bn2_kernel<<<1, 128, 0, stream>>>(sumG + l * 128, sqG + l * 128, HID, NN,
                                          og + (size_t)l * HID, ob + (size_t)l * HID,
                                          bnsc2, bnsh2);
        {
            const float* prev = (l == 0) ? nullptr : (inter + (size_t)(l - 1) * HID);
            update_kernel<<<(NN * HID + 255) / 256, 256, 0, stream>>>(
                graw, bnsc2, bnsh2, prev, inter + (size_t)l * HID, hb, NN * HID);
        }
    }

    pred_kernel<<<(NN + 31) / 32, 256, 0, stream>>>(inter, pW, pb, out, NN);
    (void)out_size;
    (void)n_in;
}